// Round 1
// baseline (1432.518 us; speedup 1.0000x reference)
//
#include <hip/hip_runtime.h>

// MixTransformerBlock on MI355X (gfx950).
// Requires ws_size >= ~416 MB (see offsets in kernel_launch).

typedef __attribute__((ext_vector_type(8))) short bf16x8;
typedef __attribute__((ext_vector_type(4))) float f32x4;

#define NTOK 32768   // B * H * W
#define CDIM 512

__device__ __forceinline__ unsigned short f2bf(float f) {
  unsigned int u = __float_as_uint(f);
  u = (u + 0x7fffu + ((u >> 16) & 1u)) >> 16;   // RNE, no NaN handling (inputs finite)
  return (unsigned short)u;
}

__device__ __forceinline__ void gload_lds16(const void* g, void* l) {
  __builtin_amdgcn_global_load_lds(
      (const __attribute__((address_space(1))) void*)g,
      (__attribute__((address_space(3))) void*)l, 16, 0, 0);
}

// ---------------------------------------------------------------- transpose
// W (K x N) f32 -> Wt (N x K) bf16
__global__ __launch_bounds__(256)
void transpose_w(const float* __restrict__ W, unsigned short* __restrict__ Wt,
                 int K, int N) {
  __shared__ float tile[64][65];
  const int n0 = blockIdx.x * 64, k0 = blockIdx.y * 64;
  const int c = threadIdx.x & 63, rb = threadIdx.x >> 6;
#pragma unroll
  for (int i = 0; i < 16; ++i) {
    int r = i * 4 + rb;
    tile[r][c] = W[(long)(k0 + r) * N + n0 + c];
  }
  __syncthreads();
#pragma unroll
  for (int i = 0; i < 16; ++i) {
    int rn = i * 4 + rb;
    Wt[(long)(n0 + rn) * K + k0 + c] = f2bf(tile[c][rn]);
  }
}

// ---------------------------------------------------------------- layernorm
// X (32768 x 512) f32 -> out bf16, per-token LN. One wave per token.
__global__ __launch_bounds__(256)
void ln_bf16(const float* __restrict__ X, const float* __restrict__ g,
             const float* __restrict__ b, unsigned short* __restrict__ out) {
  const int lane = threadIdx.x & 63;
  const int wid = threadIdx.x >> 6;
  const long t = (long)blockIdx.x * 4 + wid;
  const float* x = X + t * CDIM + lane * 8;
  float4 v0 = *(const float4*)x;
  float4 v1 = *(const float4*)(x + 4);
  float s = v0.x + v0.y + v0.z + v0.w + v1.x + v1.y + v1.z + v1.w;
  float sq = v0.x * v0.x + v0.y * v0.y + v0.z * v0.z + v0.w * v0.w +
             v1.x * v1.x + v1.y * v1.y + v1.z * v1.z + v1.w * v1.w;
#pragma unroll
  for (int off = 32; off; off >>= 1) {
    s += __shfl_xor(s, off);
    sq += __shfl_xor(sq, off);
  }
  const float mean = s * (1.0f / 512.0f);
  const float var = sq * (1.0f / 512.0f) - mean * mean;
  const float rs = rsqrtf(var + 1e-4f);
  float4 g0 = *(const float4*)(g + lane * 8);
  float4 g1 = *(const float4*)(g + lane * 8 + 4);
  float4 b0 = *(const float4*)(b + lane * 8);
  float4 b1 = *(const float4*)(b + lane * 8 + 4);
  bf16x8 r;
  r[0] = (short)f2bf((v0.x - mean) * rs * g0.x + b0.x);
  r[1] = (short)f2bf((v0.y - mean) * rs * g0.y + b0.y);
  r[2] = (short)f2bf((v0.z - mean) * rs * g0.z + b0.z);
  r[3] = (short)f2bf((v0.w - mean) * rs * g0.w + b0.w);
  r[4] = (short)f2bf((v1.x - mean) * rs * g1.x + b1.x);
  r[5] = (short)f2bf((v1.y - mean) * rs * g1.y + b1.y);
  r[6] = (short)f2bf((v1.z - mean) * rs * g1.z + b1.z);
  r[7] = (short)f2bf((v1.w - mean) * rs * g1.w + b1.w);
  *(bf16x8*)(out + t * CDIM + lane * 8) = r;
}

// ---------------------------------------------------------------- GEMM
// C(M,N) = A(M,K) @ Bt(N,K)^T, bf16 inputs, fp32 accum.
// EPI 0: out bf16 (+bias)
// EPI 1: out bf16 ((+bias)*scale)
// EPI 2: out bf16 gelu_exact(+bias)
// EPI 3: out f32  (+bias + resid)
#define GBM 128
#define GBN 128
#define GBK 64

template <int EPI>
__global__ __launch_bounds__(256)
void gemm_bt(const unsigned short* __restrict__ A,
             const unsigned short* __restrict__ Bt,
             const float* __restrict__ bias,
             const float* resid, float scale, void* outp,
             int M, int N, int K) {
  __shared__ unsigned short As[GBM][GBK];
  __shared__ unsigned short Bs[GBN][GBK];
  const int tid = threadIdx.x;
  const int lane = tid & 63;
  const int wid = tid >> 6;
  const int wr = wid >> 1, wc = wid & 1;
  const long rowBase = (long)blockIdx.y * GBM;
  const long colBase = (long)blockIdx.x * GBN;

  f32x4 acc[4][4] = {};

  const int ccol = (tid & 7) * 8;                  // element col within BK
  const unsigned short* aptr = A + rowBase * K + ccol;
  const unsigned short* bptr = Bt + colBase * K + ccol;

  for (int k0 = 0; k0 < K; k0 += GBK) {
#pragma unroll
    for (int p = 0; p < 4; ++p) {
      const int row = p * 32 + (tid >> 3);
      gload_lds16(aptr + (long)row * K + k0,
                  (char*)(&As[0][0]) + (p * 256 + wid * 64) * 16);
      gload_lds16(bptr + (long)row * K + k0,
                  (char*)(&Bs[0][0]) + (p * 256 + wid * 64) * 16);
    }
    __syncthreads();
#pragma unroll
    for (int ks = 0; ks < GBK; ks += 32) {
      bf16x8 af[4], bfr[4];
#pragma unroll
      for (int i = 0; i < 4; ++i)
        af[i] = *(const bf16x8*)(&As[wr * 64 + i * 16 + (lane & 15)][ks + (lane >> 4) * 8]);
#pragma unroll
      for (int i = 0; i < 4; ++i)
        bfr[i] = *(const bf16x8*)(&Bs[wc * 64 + i * 16 + (lane & 15)][ks + (lane >> 4) * 8]);
#pragma unroll
      for (int m = 0; m < 4; ++m)
#pragma unroll
        for (int n = 0; n < 4; ++n)
          acc[m][n] = __builtin_amdgcn_mfma_f32_16x16x32_bf16(af[m], bfr[n], acc[m][n], 0, 0, 0);
    }
    __syncthreads();
  }

  const int r0 = (lane >> 4) * 4;
  const int cn = lane & 15;
#pragma unroll
  for (int m = 0; m < 4; ++m) {
    const long rbase = rowBase + wr * 64 + m * 16 + r0;
#pragma unroll
    for (int n = 0; n < 4; ++n) {
      const long col = colBase + wc * 64 + n * 16 + cn;
      const float bv = bias[col];
#pragma unroll
      for (int r = 0; r < 4; ++r) {
        float v = acc[m][n][r] + bv;
        if constexpr (EPI == 1) v *= scale;
        if constexpr (EPI == 2) v = 0.5f * v * (1.0f + erff(v * 0.70710678118654752f));
        const long idx = (rbase + r) * (long)N + col;
        if constexpr (EPI == 3) {
          ((float*)outp)[idx] = v + resid[idx];
        } else {
          ((unsigned short*)outp)[idx] = f2bf(v);
        }
      }
    }
  }
}

// ---------------------------------------------------------------- attention
// One block per window (512 blocks). 4 waves; wave w handles heads w*4..w*4+3.
// qbuf: (32768, 512) bf16 (pre-scaled). kvbuf: (32768, 1024) bf16, k at col
// h*32, v at col 512 + h*32. obuf: (32768, 512) bf16.
__global__ __launch_bounds__(256)
void attn_win(const unsigned short* __restrict__ qbuf,
              const unsigned short* __restrict__ kvbuf,
              const float* __restrict__ nmask,
              const float* __restrict__ rpb,
              unsigned short* __restrict__ obuf) {
  __shared__ float nm_s[64];
  __shared__ unsigned short P_s[4][64][72];
  __shared__ unsigned short Vt_s[4][32][72];

  const int tid = threadIdx.x;
  const int lane = tid & 63;
  const int wid = tid >> 6;
  const int wi = blockIdx.x;
  // window base token: b*4096 + wh*8*64 + ww*8
  const int wbase = (wi >> 6) * 4096 + ((wi >> 3) & 7) * 512 + (wi & 7) * 8;

  if (tid < 64) nm_s[tid] = nmask[wbase + ((tid >> 3) << 6) + (tid & 7)];
  __syncthreads();

  const int r0 = (lane >> 4) * 4;
  const int cn = lane & 15;
  const int kb8 = (lane >> 4) * 8;

  for (int hi = 0; hi < 4; ++hi) {
    const int h = wid * 4 + hi;

    // ---- S = Q K^T  (Q rows = queries, K rows = keys; K-dim = HD = 32)
    f32x4 s[4][4] = {};
    {
      bf16x8 qa[4], kb[4];
#pragma unroll
      for (int m = 0; m < 4; ++m) {
        const int r = m * 16 + cn;
        const long tok = wbase + ((r >> 3) << 6) + (r & 7);
        qa[m] = *(const bf16x8*)(qbuf + tok * 512 + h * 32 + kb8);
      }
#pragma unroll
      for (int n = 0; n < 4; ++n) {
        const int c = n * 16 + cn;
        const long tok = wbase + ((c >> 3) << 6) + (c & 7);
        kb[n] = *(const bf16x8*)(kvbuf + tok * 1024 + h * 32 + kb8);
      }
#pragma unroll
      for (int m = 0; m < 4; ++m)
#pragma unroll
        for (int n = 0; n < 4; ++n)
          s[m][n] = __builtin_amdgcn_mfma_f32_16x16x32_bf16(qa[m], kb[n], s[m][n], 0, 0, 0);
    }

    // ---- + rel-pos bias + nuclei mask, row softmax (rows spread over 16-lane groups)
#pragma unroll
    for (int m = 0; m < 4; ++m) {
#pragma unroll
      for (int r = 0; r < 4; ++r) {
        const int q = m * 16 + r0 + r;
        const int qi = q >> 3, qj = q & 7;
        float rowv[4];
#pragma unroll
        for (int n = 0; n < 4; ++n) {
          const int k = n * 16 + cn;
          const int ki = k >> 3, kj = k & 7;
          const int ridx = (qi - ki + 7) * 15 + (qj - kj + 7);
          rowv[n] = s[m][n][r] + rpb[ridx * 16 + h] + nm_s[q] + nm_s[k];
        }
        float mx = fmaxf(fmaxf(rowv[0], rowv[1]), fmaxf(rowv[2], rowv[3]));
#pragma unroll
        for (int off = 8; off; off >>= 1) mx = fmaxf(mx, __shfl_xor(mx, off));
        float sum = 0.f;
#pragma unroll
        for (int n = 0; n < 4; ++n) { rowv[n] = __expf(rowv[n] - mx); sum += rowv[n]; }
#pragma unroll
        for (int off = 8; off; off >>= 1) sum += __shfl_xor(sum, off);
        const float inv = 1.0f / sum;
#pragma unroll
        for (int n = 0; n < 4; ++n) s[m][n][r] = rowv[n] * inv;
      }
    }

    // ---- P -> LDS (bf16, row-major [query][key], padded)
#pragma unroll
    for (int m = 0; m < 4; ++m)
#pragma unroll
      for (int n = 0; n < 4; ++n)
#pragma unroll
        for (int r = 0; r < 4; ++r)
          P_s[wid][m * 16 + r0 + r][n * 16 + cn] = f2bf(s[m][n][r]);

    // ---- V^T -> LDS  (lane = key; reads V row, scatters into [hd][key])
    {
      const long tok = wbase + ((lane >> 3) << 6) + (lane & 7);
      const unsigned short* vrow = kvbuf + tok * 1024 + 512 + h * 32;
#pragma unroll
      for (int j = 0; j < 4; ++j) {
        bf16x8 vv = *(const bf16x8*)(vrow + j * 8);
#pragma unroll
        for (int e = 0; e < 8; ++e)
          Vt_s[wid][j * 8 + e][lane] = (unsigned short)vv[e];
      }
    }

    // ---- O = P @ V  (K-dim = 64 keys = 2 MFMA steps)
    f32x4 o[4][2] = {};
#pragma unroll
    for (int t = 0; t < 2; ++t) {
      bf16x8 pa[4], vb[2];
#pragma unroll
      for (int m = 0; m < 4; ++m)
        pa[m] = *(const bf16x8*)(&P_s[wid][m * 16 + cn][t * 32 + kb8]);
#pragma unroll
      for (int n = 0; n < 2; ++n)
        vb[n] = *(const bf16x8*)(&Vt_s[wid][n * 16 + cn][t * 32 + kb8]);
#pragma unroll
      for (int m = 0; m < 4; ++m)
#pragma unroll
        for (int n = 0; n < 2; ++n)
          o[m][n] = __builtin_amdgcn_mfma_f32_16x16x32_bf16(pa[m], vb[n], o[m][n], 0, 0, 0);
    }

    // ---- write O (token-major bf16)
#pragma unroll
    for (int m = 0; m < 4; ++m) {
#pragma unroll
      for (int r = 0; r < 4; ++r) {
        const int q = m * 16 + r0 + r;
        const long tok = wbase + ((q >> 3) << 6) + (q & 7);
#pragma unroll
        for (int n = 0; n < 2; ++n)
          obuf[tok * 512 + h * 32 + n * 16 + cn] = f2bf(o[m][n][r]);
      }
    }
  }
}

// ---------------------------------------------------------------- launch
extern "C" void kernel_launch(void* const* d_in, const int* in_sizes, int n_in,
                              void* d_out, int out_size, void* d_ws, size_t ws_size,
                              hipStream_t stream) {
  const float* x = (const float*)d_in[0];
  const float* y = (const float*)d_in[1];
  const float* nmk = (const float*)d_in[2];
  const float* rpb = (const float*)d_in[3];
  const float* g1 = (const float*)d_in[4];
  const float* b1 = (const float*)d_in[5];
  const float* g3 = (const float*)d_in[6];
  const float* b3 = (const float*)d_in[7];
  const float* w_qkv = (const float*)d_in[8];
  const float* b_qkv = (const float*)d_in[9];
  const float* w_qkv_y = (const float*)d_in[10];
  const float* b_qkv_y = (const float*)d_in[11];
  const float* w_qx = (const float*)d_in[12];
  const float* b_qx = (const float*)d_in[13];
  const float* w_qy = (const float*)d_in[14];
  const float* b_qy = (const float*)d_in[15];
  const float* w_proj = (const float*)d_in[16];
  const float* b_proj = (const float*)d_in[17];
  const float* w_proj_y = (const float*)d_in[18];
  const float* b_proj_y = (const float*)d_in[19];
  const float* g2 = (const float*)d_in[20];
  const float* b2 = (const float*)d_in[21];
  const float* g4 = (const float*)d_in[22];
  const float* b4 = (const float*)d_in[23];
  const float* w_fc1 = (const float*)d_in[24];
  const float* b_fc1 = (const float*)d_in[25];
  const float* w_fc2 = (const float*)d_in[26];
  const float* b_fc2 = (const float*)d_in[27];
  const float* w_fc1y = (const float*)d_in[28];
  const float* b_fc1y = (const float*)d_in[29];
  const float* w_fc2y = (const float*)d_in[30];
  const float* b_fc2y = (const float*)d_in[31];

  char* ws = (char*)d_ws;
  unsigned short* w_qkvT   = (unsigned short*)(ws + 0);
  unsigned short* w_qkv_yT = (unsigned short*)(ws + 1048576);
  unsigned short* w_qxT    = (unsigned short*)(ws + 2097152);
  unsigned short* w_qyT    = (unsigned short*)(ws + 2621440);
  unsigned short* w_projT  = (unsigned short*)(ws + 3145728);
  unsigned short* w_projyT = (unsigned short*)(ws + 3670016);
  unsigned short* w_fc1T   = (unsigned short*)(ws + 4194304);
  unsigned short* w_fc2T   = (unsigned short*)(ws + 6291456);
  unsigned short* w_fc1yT  = (unsigned short*)(ws + 8388608);
  unsigned short* w_fc2yT  = (unsigned short*)(ws + 10485760);
  unsigned short* xln = (unsigned short*)(ws + 12582912);   // later attnout_x
  unsigned short* yln = (unsigned short*)(ws + 46137344);   // later attnout_y
  unsigned short* qx  = (unsigned short*)(ws + 79691776);   // later x2ln
  unsigned short* qy  = (unsigned short*)(ws + 113246208);  // later y2ln
  unsigned short* kvx = (unsigned short*)(ws + 146800640);  // later h_x (32768x2048)
  unsigned short* kvy = (unsigned short*)(ws + 281018368);  // later h_y

  float* out_x = (float*)d_out;
  float* out_y = out_x + 16777216;

  // 1. weight transposes (f32 KxN -> bf16 NxK)
  transpose_w<<<dim3(16, 8), 256, 0, stream>>>(w_qkv, w_qkvT, 512, 1024);
  transpose_w<<<dim3(16, 8), 256, 0, stream>>>(w_qkv_y, w_qkv_yT, 512, 1024);
  transpose_w<<<dim3(8, 8), 256, 0, stream>>>(w_qx, w_qxT, 512, 512);
  transpose_w<<<dim3(8, 8), 256, 0, stream>>>(w_qy, w_qyT, 512, 512);
  transpose_w<<<dim3(8, 8), 256, 0, stream>>>(w_proj, w_projT, 512, 512);
  transpose_w<<<dim3(8, 8), 256, 0, stream>>>(w_proj_y, w_projyT, 512, 512);
  transpose_w<<<dim3(32, 8), 256, 0, stream>>>(w_fc1, w_fc1T, 512, 2048);
  transpose_w<<<dim3(8, 32), 256, 0, stream>>>(w_fc2, w_fc2T, 2048, 512);
  transpose_w<<<dim3(32, 8), 256, 0, stream>>>(w_fc1y, w_fc1yT, 512, 2048);
  transpose_w<<<dim3(8, 32), 256, 0, stream>>>(w_fc2y, w_fc2yT, 2048, 512);

  // 2. LN1 / LN3
  ln_bf16<<<8192, 256, 0, stream>>>(x, g1, b1, xln);
  ln_bf16<<<8192, 256, 0, stream>>>(y, g3, b3, yln);

  // 3-6. kv and q projections
  gemm_bt<0><<<dim3(8, 256), 256, 0, stream>>>(xln, w_qkvT, b_qkv, nullptr, 1.f, kvx, NTOK, 1024, 512);
  gemm_bt<0><<<dim3(8, 256), 256, 0, stream>>>(yln, w_qkv_yT, b_qkv_y, nullptr, 1.f, kvy, NTOK, 1024, 512);
  const float qscale = 0.17677669529663687f;  // 1/sqrt(32)
  gemm_bt<1><<<dim3(4, 256), 256, 0, stream>>>(xln, w_qxT, b_qx, nullptr, qscale, qx, NTOK, 512, 512);
  gemm_bt<1><<<dim3(4, 256), 256, 0, stream>>>(yln, w_qyT, b_qy, nullptr, qscale, qy, NTOK, 512, 512);

  // 7. windowed attention: x-side uses q_y with k,v from x; y-side q_x with k_y,v_y
  attn_win<<<512, 256, 0, stream>>>(qy, kvx, nmk, rpb, xln);
  attn_win<<<512, 256, 0, stream>>>(qx, kvy, nmk, rpb, yln);

  // 8-9. proj + residual -> d_out (x1, y1)
  gemm_bt<3><<<dim3(4, 256), 256, 0, stream>>>(xln, w_projT, b_proj, x, 1.f, out_x, NTOK, 512, 512);
  gemm_bt<3><<<dim3(4, 256), 256, 0, stream>>>(yln, w_projyT, b_proj_y, y, 1.f, out_y, NTOK, 512, 512);

  // 10. LN2 / LN4
  ln_bf16<<<8192, 256, 0, stream>>>(out_x, g2, b2, qx);
  ln_bf16<<<8192, 256, 0, stream>>>(out_y, g4, b4, qy);

  // 11-12. fc1 + exact GELU
  gemm_bt<2><<<dim3(16, 256), 256, 0, stream>>>(qx, w_fc1T, b_fc1, nullptr, 1.f, kvx, NTOK, 2048, 512);
  gemm_bt<2><<<dim3(16, 256), 256, 0, stream>>>(qy, w_fc1yT, b_fc1y, nullptr, 1.f, kvy, NTOK, 2048, 512);

  // 13-14. fc2 + residual (in-place on d_out)
  gemm_bt<3><<<dim3(4, 256), 256, 0, stream>>>(kvx, w_fc2T, b_fc2, out_x, 1.f, out_x, NTOK, 512, 2048);
  gemm_bt<3><<<dim3(4, 256), 256, 0, stream>>>(kvy, w_fc2yT, b_fc2y, out_y, 1.f, out_y, NTOK, 512, 2048);
}

// Round 2
// 1417.288 us; speedup vs baseline: 1.0107x; 1.0107x over previous
//
#include <hip/hip_runtime.h>

// MixTransformerBlock on MI355X (gfx950).
// Round 2: double-buffered 2-phase GEMM (T3-minimum), XCD swizzle (T1),
// q fused into kv GEMM (N=1536), x/y pairs batched via gridDim.z.
// Requires ws_size >= ~416 MB.

typedef __attribute__((ext_vector_type(8))) short bf16x8;
typedef __attribute__((ext_vector_type(4))) float f32x4;

#define NTOK 32768   // B * H * W
#define CDIM 512

__device__ __forceinline__ unsigned short f2bf(float f) {
  unsigned int u = __float_as_uint(f);
  u = (u + 0x7fffu + ((u >> 16) & 1u)) >> 16;   // RNE (inputs finite)
  return (unsigned short)u;
}

__device__ __forceinline__ void gload_lds16(const void* g, void* l) {
  __builtin_amdgcn_global_load_lds(
      (const __attribute__((address_space(1))) void*)g,
      (__attribute__((address_space(3))) void*)l, 16, 0, 0);
}

// ---------------------------------------------------------------- transpose
// W (K x N) f32 -> Wt (N x K) bf16
__global__ __launch_bounds__(256)
void transpose_w(const float* __restrict__ W, unsigned short* __restrict__ Wt,
                 int K, int N) {
  __shared__ float tile[64][65];
  const int n0 = blockIdx.x * 64, k0 = blockIdx.y * 64;
  const int c = threadIdx.x & 63, rb = threadIdx.x >> 6;
#pragma unroll
  for (int i = 0; i < 16; ++i) {
    int r = i * 4 + rb;
    tile[r][c] = W[(long)(k0 + r) * N + n0 + c];
  }
  __syncthreads();
#pragma unroll
  for (int i = 0; i < 16; ++i) {
    int rn = i * 4 + rb;
    Wt[(long)(n0 + rn) * K + k0 + c] = f2bf(tile[c][rn]);
  }
}

// ---------------------------------------------------------------- layernorm
__global__ __launch_bounds__(256)
void ln_bf16(const float* __restrict__ X, const float* __restrict__ g,
             const float* __restrict__ b, unsigned short* __restrict__ out) {
  const int lane = threadIdx.x & 63;
  const int wid = threadIdx.x >> 6;
  const long t = (long)blockIdx.x * 4 + wid;
  const float* x = X + t * CDIM + lane * 8;
  float4 v0 = *(const float4*)x;
  float4 v1 = *(const float4*)(x + 4);
  float s = v0.x + v0.y + v0.z + v0.w + v1.x + v1.y + v1.z + v1.w;
  float sq = v0.x * v0.x + v0.y * v0.y + v0.z * v0.z + v0.w * v0.w +
             v1.x * v1.x + v1.y * v1.y + v1.z * v1.z + v1.w * v1.w;
#pragma unroll
  for (int off = 32; off; off >>= 1) {
    s += __shfl_xor(s, off);
    sq += __shfl_xor(sq, off);
  }
  const float mean = s * (1.0f / 512.0f);
  const float var = sq * (1.0f / 512.0f) - mean * mean;
  const float rs = rsqrtf(var + 1e-4f);
  float4 g0 = *(const float4*)(g + lane * 8);
  float4 g1 = *(const float4*)(g + lane * 8 + 4);
  float4 b0 = *(const float4*)(b + lane * 8);
  float4 b1 = *(const float4*)(b + lane * 8 + 4);
  bf16x8 r;
  r[0] = (short)f2bf((v0.x - mean) * rs * g0.x + b0.x);
  r[1] = (short)f2bf((v0.y - mean) * rs * g0.y + b0.y);
  r[2] = (short)f2bf((v0.z - mean) * rs * g0.z + b0.z);
  r[3] = (short)f2bf((v0.w - mean) * rs * g0.w + b0.w);
  r[4] = (short)f2bf((v1.x - mean) * rs * g1.x + b1.x);
  r[5] = (short)f2bf((v1.y - mean) * rs * g1.y + b1.y);
  r[6] = (short)f2bf((v1.z - mean) * rs * g1.z + b1.z);
  r[7] = (short)f2bf((v1.w - mean) * rs * g1.w + b1.w);
  *(bf16x8*)(out + t * CDIM + lane * 8) = r;
}

// ---------------------------------------------------------------- GEMM
// C(M,N) = A(M,K) @ Bt(N,K)^T, bf16 in, fp32 accum.
// EPI 2: out bf16 gelu_exact(+bias)
// EPI 3: out f32  (+bias + resid)
// EPI 4: out bf16 (+bias), * scale for cols >= 1024  (fused kv|q projection)
#define GBM 128
#define GBN 128
#define GBK 64

struct PairArgs {
  const unsigned short* A0; const unsigned short* A1;
  const unsigned short* B0; const unsigned short* B1;
  const float* bias0; const float* bias1;
  const float* r0; const float* r1;
  void* o0; void* o1;
};

template <int EPI>
__global__ __launch_bounds__(256)
void gemm_bt(PairArgs pa, float scale, int M, int N, int K) {
  __shared__ unsigned short As[2][GBM][GBK];
  __shared__ unsigned short Bs[2][GBN][GBK];

  const int z = blockIdx.z;
  const unsigned short* __restrict__ A  = z ? pa.A1 : pa.A0;
  const unsigned short* __restrict__ Bt = z ? pa.B1 : pa.B0;
  const float* __restrict__ bias = z ? pa.bias1 : pa.bias0;
  const float* resid = z ? pa.r1 : pa.r0;
  void* outp = z ? pa.o1 : pa.o0;

  // T1: bijective XCD-aware remap of the (bx,by) tile (m204 form)
  const int nwg = gridDim.x * gridDim.y;
  int wg = blockIdx.y * gridDim.x + blockIdx.x;
  {
    const int q8 = nwg >> 3, r8 = nwg & 7;
    const int xcd = wg & 7, o = wg >> 3;
    wg = (xcd < r8 ? xcd * (q8 + 1) : r8 * (q8 + 1) + (xcd - r8) * q8) + o;
  }
  const int bx = wg % gridDim.x, by = wg / gridDim.x;

  const int tid = threadIdx.x;
  const int lane = tid & 63;
  const int wid = tid >> 6;
  const int wr = wid >> 1, wc = wid & 1;
  const long rowBase = (long)by * GBM;
  const long colBase = (long)bx * GBN;

  f32x4 acc[4][4] = {};

  const unsigned short* aptr = A + rowBase * K + (tid & 7) * 8;
  const unsigned short* bptr = Bt + colBase * K + (tid & 7) * 8;
  const int ldsOff = (tid >> 3) * 64 * 16 / 64;  // unused placeholder removal

  // stage one 128x64 A-tile + B-tile into buffer `buf` for k-offset k0
  auto stage = [&](int buf, int k0) {
#pragma unroll
    for (int p = 0; p < 4; ++p) {
      const int row = p * 32 + (tid >> 3);
      gload_lds16(aptr + (long)row * K + k0,
                  (char*)(&As[buf][0][0]) + (p * 256 + wid * 64) * 16);
      gload_lds16(bptr + (long)row * K + k0,
                  (char*)(&Bs[buf][0][0]) + (p * 256 + wid * 64) * 16);
    }
  };

  const int nt = K / GBK;
  stage(0, 0);
  asm volatile("s_waitcnt vmcnt(0)" ::: "memory");
  __syncthreads();

  int cur = 0;
  for (int t = 0; t < nt; ++t) {
    if (t + 1 < nt) stage(cur ^ 1, (t + 1) * GBK);   // prefetch in flight
#pragma unroll
    for (int ks = 0; ks < GBK; ks += 32) {
      bf16x8 af[4], bfr[4];
#pragma unroll
      for (int i = 0; i < 4; ++i)
        af[i] = *(const bf16x8*)(&As[cur][wr * 64 + i * 16 + (lane & 15)][ks + (lane >> 4) * 8]);
#pragma unroll
      for (int i = 0; i < 4; ++i)
        bfr[i] = *(const bf16x8*)(&Bs[cur][wc * 64 + i * 16 + (lane & 15)][ks + (lane >> 4) * 8]);
#pragma unroll
      for (int m = 0; m < 4; ++m)
#pragma unroll
        for (int n = 0; n < 4; ++n)
          acc[m][n] = __builtin_amdgcn_mfma_f32_16x16x32_bf16(af[m], bfr[n], acc[m][n], 0, 0, 0);
    }
    if (t + 1 < nt) {
      asm volatile("s_waitcnt vmcnt(0)" ::: "memory");
      __syncthreads();
      cur ^= 1;
    }
  }

  const int r0 = (lane >> 4) * 4;
  const int cn = lane & 15;
#pragma unroll
  for (int m = 0; m < 4; ++m) {
    const long rbase = rowBase + wr * 64 + m * 16 + r0;
#pragma unroll
    for (int n = 0; n < 4; ++n) {
      const long col = colBase + wc * 64 + n * 16 + cn;
      const float bv = bias[col];
#pragma unroll
      for (int r = 0; r < 4; ++r) {
        float v = acc[m][n][r] + bv;
        if constexpr (EPI == 2) v = 0.5f * v * (1.0f + erff(v * 0.70710678118654752f));
        if constexpr (EPI == 4) { if (col >= 1024) v *= scale; }
        const long idx = (rbase + r) * (long)N + col;
        if constexpr (EPI == 3) {
          ((float*)outp)[idx] = v + resid[idx];
        } else {
          ((unsigned short*)outp)[idx] = f2bf(v);
        }
      }
    }
  }
}

// ---------------------------------------------------------------- attention
// One block per window (512). 4 waves; wave w handles heads w*4..w*4+3.
// qbuf: stride qs, pre-scaled q at col h*32. kvbuf: stride ks_, k at h*32,
// v at vOff + h*32. obuf: (32768, 512) bf16.
__global__ __launch_bounds__(256)
void attn_win(const unsigned short* __restrict__ qbuf, int qs,
              const unsigned short* __restrict__ kvbuf, int ks_, int vOff,
              const float* __restrict__ nmask,
              const float* __restrict__ rpb,
              unsigned short* __restrict__ obuf) {
  __shared__ float nm_s[64];
  __shared__ unsigned short P_s[4][64][72];
  __shared__ unsigned short Vt_s[4][32][72];

  const int tid = threadIdx.x;
  const int lane = tid & 63;
  const int wid = tid >> 6;
  const int wi = blockIdx.x;
  const int wbase = (wi >> 6) * 4096 + ((wi >> 3) & 7) * 512 + (wi & 7) * 8;

  if (tid < 64) nm_s[tid] = nmask[wbase + ((tid >> 3) << 6) + (tid & 7)];
  __syncthreads();

  const int r0 = (lane >> 4) * 4;
  const int cn = lane & 15;
  const int kb8 = (lane >> 4) * 8;

  for (int hi = 0; hi < 4; ++hi) {
    const int h = wid * 4 + hi;

    f32x4 s[4][4] = {};
    {
      bf16x8 qa[4], kb[4];
#pragma unroll
      for (int m = 0; m < 4; ++m) {
        const int r = m * 16 + cn;
        const long tok = wbase + ((r >> 3) << 6) + (r & 7);
        qa[m] = *(const bf16x8*)(qbuf + tok * qs + h * 32 + kb8);
      }
#pragma unroll
      for (int n = 0; n < 4; ++n) {
        const int c = n * 16 + cn;
        const long tok = wbase + ((c >> 3) << 6) + (c & 7);
        kb[n] = *(const bf16x8*)(kvbuf + tok * ks_ + h * 32 + kb8);
      }
#pragma unroll
      for (int m = 0; m < 4; ++m)
#pragma unroll
        for (int n = 0; n < 4; ++n)
          s[m][n] = __builtin_amdgcn_mfma_f32_16x16x32_bf16(qa[m], kb[n], s[m][n], 0, 0, 0);
    }

#pragma unroll
    for (int m = 0; m < 4; ++m) {
#pragma unroll
      for (int r = 0; r < 4; ++r) {
        const int q = m * 16 + r0 + r;
        const int qi = q >> 3, qj = q & 7;
        float rowv[4];
#pragma unroll
        for (int n = 0; n < 4; ++n) {
          const int k = n * 16 + cn;
          const int ki = k >> 3, kj = k & 7;
          const int ridx = (qi - ki + 7) * 15 + (qj - kj + 7);
          rowv[n] = s[m][n][r] + rpb[ridx * 16 + h] + nm_s[q] + nm_s[k];
        }
        float mx = fmaxf(fmaxf(rowv[0], rowv[1]), fmaxf(rowv[2], rowv[3]));
#pragma unroll
        for (int off = 8; off; off >>= 1) mx = fmaxf(mx, __shfl_xor(mx, off));
        float sum = 0.f;
#pragma unroll
        for (int n = 0; n < 4; ++n) { rowv[n] = __expf(rowv[n] - mx); sum += rowv[n]; }
#pragma unroll
        for (int off = 8; off; off >>= 1) sum += __shfl_xor(sum, off);
        const float inv = 1.0f / sum;
#pragma unroll
        for (int n = 0; n < 4; ++n) s[m][n][r] = rowv[n] * inv;
      }
    }

#pragma unroll
    for (int m = 0; m < 4; ++m)
#pragma unroll
      for (int n = 0; n < 4; ++n)
#pragma unroll
        for (int r = 0; r < 4; ++r)
          P_s[wid][m * 16 + r0 + r][n * 16 + cn] = f2bf(s[m][n][r]);

    {
      const long tok = wbase + ((lane >> 3) << 6) + (lane & 7);
      const unsigned short* vrow = kvbuf + tok * ks_ + vOff + h * 32;
#pragma unroll
      for (int j = 0; j < 4; ++j) {
        bf16x8 vv = *(const bf16x8*)(vrow + j * 8);
#pragma unroll
        for (int e = 0; e < 8; ++e)
          Vt_s[wid][j * 8 + e][lane] = (unsigned short)vv[e];
      }
    }

    f32x4 o[4][2] = {};
#pragma unroll
    for (int t = 0; t < 2; ++t) {
      bf16x8 pa[4], vb[2];
#pragma unroll
      for (int m = 0; m < 4; ++m)
        pa[m] = *(const bf16x8*)(&P_s[wid][m * 16 + cn][t * 32 + kb8]);
#pragma unroll
      for (int n = 0; n < 2; ++n)
        vb[n] = *(const bf16x8*)(&Vt_s[wid][n * 16 + cn][t * 32 + kb8]);
#pragma unroll
      for (int m = 0; m < 4; ++m)
#pragma unroll
        for (int n = 0; n < 2; ++n)
          o[m][n] = __builtin_amdgcn_mfma_f32_16x16x32_bf16(pa[m], vb[n], o[m][n], 0, 0, 0);
    }

#pragma unroll
    for (int m = 0; m < 4; ++m) {
#pragma unroll
      for (int r = 0; r < 4; ++r) {
        const int q = m * 16 + r0 + r;
        const long tok = wbase + ((q >> 3) << 6) + (q & 7);
#pragma unroll
        for (int n = 0; n < 2; ++n)
          obuf[tok * 512 + h * 32 + n * 16 + cn] = f2bf(o[m][n][r]);
      }
    }
  }
}

// ---------------------------------------------------------------- launch
extern "C" void kernel_launch(void* const* d_in, const int* in_sizes, int n_in,
                              void* d_out, int out_size, void* d_ws, size_t ws_size,
                              hipStream_t stream) {
  const float* x = (const float*)d_in[0];
  const float* y = (const float*)d_in[1];
  const float* nmk = (const float*)d_in[2];
  const float* rpb = (const float*)d_in[3];
  const float* g1 = (const float*)d_in[4];
  const float* b1 = (const float*)d_in[5];
  const float* g3 = (const float*)d_in[6];
  const float* b3 = (const float*)d_in[7];
  const float* w_qkv = (const float*)d_in[8];
  const float* b_qkv = (const float*)d_in[9];
  const float* w_qkv_y = (const float*)d_in[10];
  const float* b_qkv_y = (const float*)d_in[11];
  const float* w_qx = (const float*)d_in[12];
  const float* b_qx = (const float*)d_in[13];
  const float* w_qy = (const float*)d_in[14];
  const float* b_qy = (const float*)d_in[15];
  const float* w_proj = (const float*)d_in[16];
  const float* b_proj = (const float*)d_in[17];
  const float* w_proj_y = (const float*)d_in[18];
  const float* b_proj_y = (const float*)d_in[19];
  const float* g2 = (const float*)d_in[20];
  const float* b2 = (const float*)d_in[21];
  const float* g4 = (const float*)d_in[22];
  const float* b4 = (const float*)d_in[23];
  const float* w_fc1 = (const float*)d_in[24];
  const float* b_fc1 = (const float*)d_in[25];
  const float* w_fc2 = (const float*)d_in[26];
  const float* b_fc2 = (const float*)d_in[27];
  const float* w_fc1y = (const float*)d_in[28];
  const float* b_fc1y = (const float*)d_in[29];
  const float* w_fc2y = (const float*)d_in[30];
  const float* b_fc2y = (const float*)d_in[31];

  char* ws = (char*)d_ws;
  // weights (bf16, N x K layout)
  unsigned short* wT_kvq_x = (unsigned short*)(ws + 0);          // 1536x512
  unsigned short* wT_kvq_y = (unsigned short*)(ws + 1572864);    // 1536x512
  unsigned short* w_projT  = (unsigned short*)(ws + 3145728);    // 512x512
  unsigned short* w_projyT = (unsigned short*)(ws + 3670016);
  unsigned short* w_fc1T   = (unsigned short*)(ws + 4194304);    // 2048x512
  unsigned short* w_fc2T   = (unsigned short*)(ws + 6291456);    // 512x2048
  unsigned short* w_fc1yT  = (unsigned short*)(ws + 8388608);
  unsigned short* w_fc2yT  = (unsigned short*)(ws + 10485760);
  float* bias_kvq_x = (float*)(ws + 12582912);                   // 1536 f32
  float* bias_kvq_y = (float*)(ws + 12589056);                   // 1536 f32
  // activations
  unsigned short* XLN  = (unsigned short*)(ws + 12595200);   // 32768x512; later attnout_x
  unsigned short* YLN  = (unsigned short*)(ws + 46149632);   // 32768x512; later attnout_y
  unsigned short* KVQX = (unsigned short*)(ws + 79704064);   // 32768x1536; later x2ln
  unsigned short* KVQY = (unsigned short*)(ws + 180367360);  // 32768x1536; later y2ln
  unsigned short* HBUF = (unsigned short*)(ws + 281030656);  // 32768x2048, shared x->y

  float* out_x = (float*)d_out;
  float* out_y = out_x + 16777216;

  // 1. weight transposes (f32 KxN -> bf16 NxK); q fused behind kv
  transpose_w<<<dim3(16, 8), 256, 0, stream>>>(w_qkv, wT_kvq_x, 512, 1024);
  transpose_w<<<dim3(8, 8), 256, 0, stream>>>(w_qx, wT_kvq_x + 1024 * 512, 512, 512);
  transpose_w<<<dim3(16, 8), 256, 0, stream>>>(w_qkv_y, wT_kvq_y, 512, 1024);
  transpose_w<<<dim3(8, 8), 256, 0, stream>>>(w_qy, wT_kvq_y + 1024 * 512, 512, 512);
  transpose_w<<<dim3(8, 8), 256, 0, stream>>>(w_proj, w_projT, 512, 512);
  transpose_w<<<dim3(8, 8), 256, 0, stream>>>(w_proj_y, w_projyT, 512, 512);
  transpose_w<<<dim3(32, 8), 256, 0, stream>>>(w_fc1, w_fc1T, 512, 2048);
  transpose_w<<<dim3(8, 32), 256, 0, stream>>>(w_fc2, w_fc2T, 2048, 512);
  transpose_w<<<dim3(32, 8), 256, 0, stream>>>(w_fc1y, w_fc1yT, 512, 2048);
  transpose_w<<<dim3(8, 32), 256, 0, stream>>>(w_fc2y, w_fc2yT, 2048, 512);

  // fused bias vectors [b_kv | b_q]
  hipMemcpyAsync(bias_kvq_x, b_qkv, 1024 * 4, hipMemcpyDeviceToDevice, stream);
  hipMemcpyAsync(bias_kvq_x + 1024, b_qx, 512 * 4, hipMemcpyDeviceToDevice, stream);
  hipMemcpyAsync(bias_kvq_y, b_qkv_y, 1024 * 4, hipMemcpyDeviceToDevice, stream);
  hipMemcpyAsync(bias_kvq_y + 1024, b_qy, 512 * 4, hipMemcpyDeviceToDevice, stream);

  // 2. LN1 / LN3
  ln_bf16<<<8192, 256, 0, stream>>>(x, g1, b1, XLN);
  ln_bf16<<<8192, 256, 0, stream>>>(y, g3, b3, YLN);

  // 3. fused kv|q projections, x & y batched (z)
  const float qscale = 0.17677669529663687f;  // 1/sqrt(32)
  {
    PairArgs pa{XLN, YLN, wT_kvq_x, wT_kvq_y, bias_kvq_x, bias_kvq_y,
                nullptr, nullptr, KVQX, KVQY};
    gemm_bt<4><<<dim3(12, 256, 2), 256, 0, stream>>>(pa, qscale, NTOK, 1536, 512);
  }

  // 4. windowed attention (x-side uses q_y with k,v from x; y-side vice versa)
  attn_win<<<512, 256, 0, stream>>>(KVQY + 1024, 1536, KVQX, 1536, 512, nmk, rpb, XLN);
  attn_win<<<512, 256, 0, stream>>>(KVQX + 1024, 1536, KVQY, 1536, 512, nmk, rpb, YLN);

  // 5. proj + residual -> d_out, batched
  {
    PairArgs pa{XLN, YLN, w_projT, w_projyT, b_proj, b_proj_y, x, y, out_x, out_y};
    gemm_bt<3><<<dim3(4, 256, 2), 256, 0, stream>>>(pa, 1.f, NTOK, 512, 512);
  }

  // 6. LN2 / LN4 (into dead KVQ areas)
  ln_bf16<<<8192, 256, 0, stream>>>(out_x, g2, b2, KVQX);
  ln_bf16<<<8192, 256, 0, stream>>>(out_y, g4, b4, KVQY);

  // 7. MLP x (sequential to share HBUF)
  {
    PairArgs pa{KVQX, KVQX, w_fc1T, w_fc1T, b_fc1, b_fc1, nullptr, nullptr, HBUF, HBUF};
    gemm_bt<2><<<dim3(16, 256, 1), 256, 0, stream>>>(pa, 1.f, NTOK, 2048, 512);
  }
  {
    PairArgs pa{HBUF, HBUF, w_fc2T, w_fc2T, b_fc2, b_fc2, out_x, out_x, out_x, out_x};
    gemm_bt<3><<<dim3(4, 256, 1), 256, 0, stream>>>(pa, 1.f, NTOK, 512, 2048);
  }
  // 8. MLP y
  {
    PairArgs pa{KVQY, KVQY, w_fc1yT, w_fc1yT, b_fc1y, b_fc1y, nullptr, nullptr, HBUF, HBUF};
    gemm_bt<2><<<dim3(16, 256, 1), 256, 0, stream>>>(pa, 1.f, NTOK, 2048, 512);
  }
  {
    PairArgs pa{HBUF, HBUF, w_fc2yT, w_fc2yT, b_fc2y, b_fc2y, out_y, out_y, out_y, out_y};
    gemm_bt<3><<<dim3(4, 256, 1), 256, 0, stream>>>(pa, 1.f, NTOK, 512, 2048);
  }
}

// Round 3
// 1193.030 us; speedup vs baseline: 1.2007x; 1.1880x over previous
//
#include <hip/hip_runtime.h>

// MixTransformerBlock on MI355X (gfx950).
// Round 3: all GEMMs on the 256x256 8-phase template (T2 swizzle + T3/T4
// counted-vmcnt phases + T5 setprio), derived from the m201 recipe.
// Requires ws_size >= ~416 MB.

typedef __attribute__((ext_vector_type(8))) short bf16x8;
typedef __attribute__((ext_vector_type(4))) float f32x4;

#define NTOK 32768   // B * H * W
#define CDIM 512

__device__ __forceinline__ unsigned short f2bf(float f) {
  unsigned int u = __float_as_uint(f);
  u = (u + 0x7fffu + ((u >> 16) & 1u)) >> 16;   // RNE (inputs finite)
  return (unsigned short)u;
}

__device__ __forceinline__ void gload_lds16(const void* g, void* l) {
  __builtin_amdgcn_global_load_lds(
      (const __attribute__((address_space(1))) void*)g,
      (__attribute__((address_space(3))) void*)l, 16, 0, 0);
}

// ---------------------------------------------------------------- transpose
__global__ __launch_bounds__(256)
void transpose_w(const float* __restrict__ W, unsigned short* __restrict__ Wt,
                 int K, int N) {
  __shared__ float tile[64][65];
  const int n0 = blockIdx.x * 64, k0 = blockIdx.y * 64;
  const int c = threadIdx.x & 63, rb = threadIdx.x >> 6;
#pragma unroll
  for (int i = 0; i < 16; ++i) {
    int r = i * 4 + rb;
    tile[r][c] = W[(long)(k0 + r) * N + n0 + c];
  }
  __syncthreads();
#pragma unroll
  for (int i = 0; i < 16; ++i) {
    int rn = i * 4 + rb;
    Wt[(long)(n0 + rn) * K + k0 + c] = f2bf(tile[c][rn]);
  }
}

// ---------------------------------------------------------------- layernorm
__global__ __launch_bounds__(256)
void ln_bf16(const float* __restrict__ X, const float* __restrict__ g,
             const float* __restrict__ b, unsigned short* __restrict__ out) {
  const int lane = threadIdx.x & 63;
  const int wid = threadIdx.x >> 6;
  const long t = (long)blockIdx.x * 4 + wid;
  const float* x = X + t * CDIM + lane * 8;
  float4 v0 = *(const float4*)x;
  float4 v1 = *(const float4*)(x + 4);
  float s = v0.x + v0.y + v0.z + v0.w + v1.x + v1.y + v1.z + v1.w;
  float sq = v0.x * v0.x + v0.y * v0.y + v0.z * v0.z + v0.w * v0.w +
             v1.x * v1.x + v1.y * v1.y + v1.z * v1.z + v1.w * v1.w;
#pragma unroll
  for (int off = 32; off; off >>= 1) {
    s += __shfl_xor(s, off);
    sq += __shfl_xor(sq, off);
  }
  const float mean = s * (1.0f / 512.0f);
  const float var = sq * (1.0f / 512.0f) - mean * mean;
  const float rs = rsqrtf(var + 1e-4f);
  float4 g0 = *(const float4*)(g + lane * 8);
  float4 g1 = *(const float4*)(g + lane * 8 + 4);
  float4 b0 = *(const float4*)(b + lane * 8);
  float4 b1 = *(const float4*)(b + lane * 8 + 4);
  bf16x8 r;
  r[0] = (short)f2bf((v0.x - mean) * rs * g0.x + b0.x);
  r[1] = (short)f2bf((v0.y - mean) * rs * g0.y + b0.y);
  r[2] = (short)f2bf((v0.z - mean) * rs * g0.z + b0.z);
  r[3] = (short)f2bf((v0.w - mean) * rs * g0.w + b0.w);
  r[4] = (short)f2bf((v1.x - mean) * rs * g1.x + b1.x);
  r[5] = (short)f2bf((v1.y - mean) * rs * g1.y + b1.y);
  r[6] = (short)f2bf((v1.z - mean) * rs * g1.z + b1.z);
  r[7] = (short)f2bf((v1.w - mean) * rs * g1.w + b1.w);
  *(bf16x8*)(out + t * CDIM + lane * 8) = r;
}

// ---------------------------------------------------------------- GEMM 256^2
// C(M,N) = A(M,K) @ Bt(N,K)^T, bf16 in, fp32 accum. 8-phase schedule.
// EPI 2: out bf16 gelu_exact(+bias)
// EPI 3: out f32  (+bias + resid)
// EPI 4: out bf16 (+bias), * scale for cols >= 1024  (fused kv|q projection)

struct PairArgs {
  const unsigned short* A0; const unsigned short* A1;
  const unsigned short* B0; const unsigned short* B1;
  const float* bias0; const float* bias1;
  const float* r0; const float* r1;
  void* o0; void* o1;
};

template <int EPI>
__global__ __launch_bounds__(512, 2)
void gemm256(PairArgs pa, float scale, int M, int N, int K) {
  // LDS: [buf][A:32K | B:32K], 128 KiB total. Linear dest for global_load_lds;
  // T2 swizzle realized as inverse-permuted global SOURCE + XOR on ds_read.
  __shared__ __attribute__((aligned(16))) char lds[131072];

  const int z = blockIdx.z;
  const unsigned short* __restrict__ A  = z ? pa.A1 : pa.A0;
  const unsigned short* __restrict__ Bt = z ? pa.B1 : pa.B0;
  const float* __restrict__ bias = z ? pa.bias1 : pa.bias0;
  const float* resid = z ? pa.r1 : pa.r0;
  void* outp = z ? pa.o1 : pa.o0;

  // T1: bijective XCD-aware remap (m204 form)
  const int nwg = gridDim.x * gridDim.y;
  int wg = blockIdx.y * gridDim.x + blockIdx.x;
  {
    const int q8 = nwg >> 3, r8 = nwg & 7;
    const int xcd = wg & 7, o = wg >> 3;
    wg = (xcd < r8 ? xcd * (q8 + 1) : r8 * (q8 + 1) + (xcd - r8) * q8) + o;
  }
  const int bx = wg % gridDim.x, by = wg / gridDim.x;

  const int tid = threadIdx.x;
  const int lane = tid & 63;
  const int wid = tid >> 6;        // 0..7
  const int wr = wid >> 2;         // 0..1  (M half)
  const int wc = wid & 3;          // 0..3  (N quarter)
  const long rowBase = (long)by * 256;
  const long colBase = (long)bx * 256;

  const unsigned short* Ap = A + rowBase * K;
  const unsigned short* Bp = Bt + colBase * K;

  // staging: each load instr covers 64 rows (512thr x 16B). Lane l of wave w
  // writes LDS linearly at (i*64 + w*8 + l/8)*128 + (l%8)*16; the global
  // source col-slot is XOR-permuted so that reads with the same XOR are
  // conflict-free (involution, rule #21).
  const int srow = wid * 8 + (lane >> 3);
  const int scol = ((lane & 7) ^ (lane >> 3)) * 8;   // elems
  const int sdst = wid * 1024;

  auto stA = [&](int buf, int k0, int i) {
    gload_lds16(Ap + (long)(i * 64 + srow) * K + k0 + scol,
                lds + buf * 65536 + i * 8192 + sdst);
  };
  auto stB = [&](int buf, int k0, int i) {
    gload_lds16(Bp + (long)(i * 64 + srow) * K + k0 + scol,
                lds + buf * 65536 + 32768 + i * 8192 + sdst);
  };

  // fragment read addressing: row = base + lane&15, k-slot = kk*4 + lane>>4,
  // physical slot = slot ^ (row&7) = slot ^ (lane&7).
  const int lo = lane & 15;
  const int hi = lane >> 4;
  const int x7 = lane & 7;
  const int arow0 = (wr * 128 + lo) * 128;   // bytes within A region
  const int brow0 = (wc * 64 + lo) * 128;    // bytes within B region

  f32x4 acc[8][4] = {};
  bf16x8 aA[4][2], bB0[2][2], bB1[2][2];

  const int nt = K / 64;

  // prologue: tile 0 -> buf 0, issue order A0,A2,B0,B1,B2,B3,A1,A3
  stA(0, 0, 0); stA(0, 0, 2); stB(0, 0, 0); stB(0, 0, 1);
  stB(0, 0, 2); stB(0, 0, 3); stA(0, 0, 1); stA(0, 0, 3);

  for (int t = 0; t < nt; ++t) {
    const int cur = t & 1;
    const int abase = cur * 65536;
    const int bbase = cur * 65536 + 32768;
    const int k1 = (t + 1) * 64;

    // -------- phase 0: first 6 loads of tile t are ready (A0,A2,B0..B3)
    asm volatile("s_waitcnt vmcnt(2)" ::: "memory");
    __builtin_amdgcn_s_barrier();
    __builtin_amdgcn_sched_barrier(0);
#pragma unroll
    for (int kk = 0; kk < 2; ++kk) {
      const int cb = ((kk * 4 + hi) ^ x7) * 16;
#pragma unroll
      for (int m = 0; m < 4; ++m)
        aA[m][kk] = *(const bf16x8*)(lds + abase + arow0 + m * 2048 + cb);
#pragma unroll
      for (int n = 0; n < 2; ++n)
        bB0[n][kk] = *(const bf16x8*)(lds + bbase + brow0 + n * 2048 + cb);
    }
    __builtin_amdgcn_s_setprio(1);
#pragma unroll
    for (int kk = 0; kk < 2; ++kk)
#pragma unroll
      for (int m = 0; m < 4; ++m)
#pragma unroll
        for (int n = 0; n < 2; ++n)
          acc[m][n] = __builtin_amdgcn_mfma_f32_16x16x32_bf16(aA[m][kk], bB0[n][kk], acc[m][n], 0, 0, 0);
    __builtin_amdgcn_s_setprio(0);
    __builtin_amdgcn_s_barrier();

    // -------- phase 1
#pragma unroll
    for (int kk = 0; kk < 2; ++kk) {
      const int cb = ((kk * 4 + hi) ^ x7) * 16;
#pragma unroll
      for (int n = 0; n < 2; ++n)
        bB1[n][kk] = *(const bf16x8*)(lds + bbase + brow0 + 4096 + n * 2048 + cb);
    }
    __builtin_amdgcn_s_setprio(1);
#pragma unroll
    for (int kk = 0; kk < 2; ++kk)
#pragma unroll
      for (int m = 0; m < 4; ++m)
#pragma unroll
        for (int n = 0; n < 2; ++n)
          acc[m][2 + n] = __builtin_amdgcn_mfma_f32_16x16x32_bf16(aA[m][kk], bB1[n][kk], acc[m][2 + n], 0, 0, 0);
    __builtin_amdgcn_s_setprio(0);
    __builtin_amdgcn_s_barrier();

    // -------- phase 2: stage first half of tile t+1, then ensure A1,A3 of t
    if (t + 1 < nt) {
      stA(cur ^ 1, k1, 0); stA(cur ^ 1, k1, 2);
      stB(cur ^ 1, k1, 0); stB(cur ^ 1, k1, 1);
      asm volatile("s_waitcnt vmcnt(4)" ::: "memory");
    } else {
      asm volatile("s_waitcnt vmcnt(0)" ::: "memory");
    }
    __builtin_amdgcn_s_barrier();
    __builtin_amdgcn_sched_barrier(0);
#pragma unroll
    for (int kk = 0; kk < 2; ++kk) {
      const int cb = ((kk * 4 + hi) ^ x7) * 16;
#pragma unroll
      for (int m = 0; m < 4; ++m)
        aA[m][kk] = *(const bf16x8*)(lds + abase + arow0 + 8192 + m * 2048 + cb);
    }
    __builtin_amdgcn_s_setprio(1);
#pragma unroll
    for (int kk = 0; kk < 2; ++kk)
#pragma unroll
      for (int m = 0; m < 4; ++m)
#pragma unroll
        for (int n = 0; n < 2; ++n)
          acc[4 + m][2 + n] = __builtin_amdgcn_mfma_f32_16x16x32_bf16(aA[m][kk], bB1[n][kk], acc[4 + m][2 + n], 0, 0, 0);
    __builtin_amdgcn_s_setprio(0);
    __builtin_amdgcn_s_barrier();

    // -------- phase 3: stage second half of tile t+1; compute on regs only
    if (t + 1 < nt) {
      stB(cur ^ 1, k1, 2); stB(cur ^ 1, k1, 3);
      stA(cur ^ 1, k1, 1); stA(cur ^ 1, k1, 3);
    }
    __builtin_amdgcn_s_setprio(1);
#pragma unroll
    for (int kk = 0; kk < 2; ++kk)
#pragma unroll
      for (int m = 0; m < 4; ++m)
#pragma unroll
        for (int n = 0; n < 2; ++n)
          acc[4 + m][n] = __builtin_amdgcn_mfma_f32_16x16x32_bf16(aA[m][kk], bB0[n][kk], acc[4 + m][n], 0, 0, 0);
    __builtin_amdgcn_s_setprio(0);
  }

  // -------- epilogue
#pragma unroll
  for (int m = 0; m < 8; ++m) {
    const long rbase = rowBase + wr * 128 + m * 16 + hi * 4;
#pragma unroll
    for (int n = 0; n < 4; ++n) {
      const long col = colBase + wc * 64 + n * 16 + lo;
      const float bv = bias[col];
#pragma unroll
      for (int r = 0; r < 4; ++r) {
        float v = acc[m][n][r] + bv;
        if constexpr (EPI == 2) v = 0.5f * v * (1.0f + erff(v * 0.70710678118654752f));
        if constexpr (EPI == 4) { if (col >= 1024) v *= scale; }
        const long idx = (rbase + r) * (long)N + col;
        if constexpr (EPI == 3) {
          ((float*)outp)[idx] = v + resid[idx];
        } else {
          ((unsigned short*)outp)[idx] = f2bf(v);
        }
      }
    }
  }
}

// ---------------------------------------------------------------- attention
__global__ __launch_bounds__(256)
void attn_win(const unsigned short* __restrict__ qbuf, int qs,
              const unsigned short* __restrict__ kvbuf, int ks_, int vOff,
              const float* __restrict__ nmask,
              const float* __restrict__ rpb,
              unsigned short* __restrict__ obuf) {
  __shared__ float nm_s[64];
  __shared__ unsigned short P_s[4][64][72];
  __shared__ unsigned short Vt_s[4][32][72];

  const int tid = threadIdx.x;
  const int lane = tid & 63;
  const int wid = tid >> 6;
  const int wi = blockIdx.x;
  const int wbase = (wi >> 6) * 4096 + ((wi >> 3) & 7) * 512 + (wi & 7) * 8;

  if (tid < 64) nm_s[tid] = nmask[wbase + ((tid >> 3) << 6) + (tid & 7)];
  __syncthreads();

  const int r0 = (lane >> 4) * 4;
  const int cn = lane & 15;
  const int kb8 = (lane >> 4) * 8;

  for (int hi = 0; hi < 4; ++hi) {
    const int h = wid * 4 + hi;

    f32x4 s[4][4] = {};
    {
      bf16x8 qa[4], kb[4];
#pragma unroll
      for (int m = 0; m < 4; ++m) {
        const int r = m * 16 + cn;
        const long tok = wbase + ((r >> 3) << 6) + (r & 7);
        qa[m] = *(const bf16x8*)(qbuf + tok * qs + h * 32 + kb8);
      }
#pragma unroll
      for (int n = 0; n < 4; ++n) {
        const int c = n * 16 + cn;
        const long tok = wbase + ((c >> 3) << 6) + (c & 7);
        kb[n] = *(const bf16x8*)(kvbuf + tok * ks_ + h * 32 + kb8);
      }
#pragma unroll
      for (int m = 0; m < 4; ++m)
#pragma unroll
        for (int n = 0; n < 4; ++n)
          s[m][n] = __builtin_amdgcn_mfma_f32_16x16x32_bf16(qa[m], kb[n], s[m][n], 0, 0, 0);
    }

#pragma unroll
    for (int m = 0; m < 4; ++m) {
#pragma unroll
      for (int r = 0; r < 4; ++r) {
        const int q = m * 16 + r0 + r;
        const int qi = q >> 3, qj = q & 7;
        float rowv[4];
#pragma unroll
        for (int n = 0; n < 4; ++n) {
          const int k = n * 16 + cn;
          const int ki = k >> 3, kj = k & 7;
          const int ridx = (qi - ki + 7) * 15 + (qj - kj + 7);
          rowv[n] = s[m][n][r] + rpb[ridx * 16 + h] + nm_s[q] + nm_s[k];
        }
        float mx = fmaxf(fmaxf(rowv[0], rowv[1]), fmaxf(rowv[2], rowv[3]));
#pragma unroll
        for (int off = 8; off; off >>= 1) mx = fmaxf(mx, __shfl_xor(mx, off));
        float sum = 0.f;
#pragma unroll
        for (int n = 0; n < 4; ++n) { rowv[n] = __expf(rowv[n] - mx); sum += rowv[n]; }
#pragma unroll
        for (int off = 8; off; off >>= 1) sum += __shfl_xor(sum, off);
        const float inv = 1.0f / sum;
#pragma unroll
        for (int n = 0; n < 4; ++n) s[m][n][r] = rowv[n] * inv;
      }
    }

#pragma unroll
    for (int m = 0; m < 4; ++m)
#pragma unroll
      for (int n = 0; n < 4; ++n)
#pragma unroll
        for (int r = 0; r < 4; ++r)
          P_s[wid][m * 16 + r0 + r][n * 16 + cn] = f2bf(s[m][n][r]);

    {
      const long tok = wbase + ((lane >> 3) << 6) + (lane & 7);
      const unsigned short* vrow = kvbuf + tok * ks_ + vOff + h * 32;
#pragma unroll
      for (int j = 0; j < 4; ++j) {
        bf16x8 vv = *(const bf16x8*)(vrow + j * 8);
#pragma unroll
        for (int e = 0; e < 8; ++e)
          Vt_s[wid][j * 8 + e][lane] = (unsigned short)vv[e];
      }
    }

    f32x4 o[4][2] = {};
#pragma unroll
    for (int t = 0; t < 2; ++t) {
      bf16x8 pa[4], vb[2];
#pragma unroll
      for (int m = 0; m < 4; ++m)
        pa[m] = *(const bf16x8*)(&P_s[wid][m * 16 + cn][t * 32 + kb8]);
#pragma unroll
      for (int n = 0; n < 2; ++n)
        vb[n] = *(const bf16x8*)(&Vt_s[wid][n * 16 + cn][t * 32 + kb8]);
#pragma unroll
      for (int m = 0; m < 4; ++m)
#pragma unroll
        for (int n = 0; n < 2; ++n)
          o[m][n] = __builtin_amdgcn_mfma_f32_16x16x32_bf16(pa[m], vb[n], o[m][n], 0, 0, 0);
    }

#pragma unroll
    for (int m = 0; m < 4; ++m) {
#pragma unroll
      for (int r = 0; r < 4; ++r) {
        const int q = m * 16 + r0 + r;
        const long tok = wbase + ((q >> 3) << 6) + (q & 7);
#pragma unroll
        for (int n = 0; n < 2; ++n)
          obuf[tok * 512 + h * 32 + n * 16 + cn] = f2bf(o[m][n][r]);
      }
    }
  }
}

// ---------------------------------------------------------------- launch
extern "C" void kernel_launch(void* const* d_in, const int* in_sizes, int n_in,
                              void* d_out, int out_size, void* d_ws, size_t ws_size,
                              hipStream_t stream) {
  const float* x = (const float*)d_in[0];
  const float* y = (const float*)d_in[1];
  const float* nmk = (const float*)d_in[2];
  const float* rpb = (const float*)d_in[3];
  const float* g1 = (const float*)d_in[4];
  const float* b1 = (const float*)d_in[5];
  const float* g3 = (const float*)d_in[6];
  const float* b3 = (const float*)d_in[7];
  const float* w_qkv = (const float*)d_in[8];
  const float* b_qkv = (const float*)d_in[9];
  const float* w_qkv_y = (const float*)d_in[10];
  const float* b_qkv_y = (const float*)d_in[11];
  const float* w_qx = (const float*)d_in[12];
  const float* b_qx = (const float*)d_in[13];
  const float* w_qy = (const float*)d_in[14];
  const float* b_qy = (const float*)d_in[15];
  const float* w_proj = (const float*)d_in[16];
  const float* b_proj = (const float*)d_in[17];
  const float* w_proj_y = (const float*)d_in[18];
  const float* b_proj_y = (const float*)d_in[19];
  const float* g2 = (const float*)d_in[20];
  const float* b2 = (const float*)d_in[21];
  const float* g4 = (const float*)d_in[22];
  const float* b4 = (const float*)d_in[23];
  const float* w_fc1 = (const float*)d_in[24];
  const float* b_fc1 = (const float*)d_in[25];
  const float* w_fc2 = (const float*)d_in[26];
  const float* b_fc2 = (const float*)d_in[27];
  const float* w_fc1y = (const float*)d_in[28];
  const float* b_fc1y = (const float*)d_in[29];
  const float* w_fc2y = (const float*)d_in[30];
  const float* b_fc2y = (const float*)d_in[31];

  char* ws = (char*)d_ws;
  unsigned short* wT_kvq_x = (unsigned short*)(ws + 0);          // 1536x512
  unsigned short* wT_kvq_y = (unsigned short*)(ws + 1572864);    // 1536x512
  unsigned short* w_projT  = (unsigned short*)(ws + 3145728);    // 512x512
  unsigned short* w_projyT = (unsigned short*)(ws + 3670016);
  unsigned short* w_fc1T   = (unsigned short*)(ws + 4194304);    // 2048x512
  unsigned short* w_fc2T   = (unsigned short*)(ws + 6291456);    // 512x2048
  unsigned short* w_fc1yT  = (unsigned short*)(ws + 8388608);
  unsigned short* w_fc2yT  = (unsigned short*)(ws + 10485760);
  float* bias_kvq_x = (float*)(ws + 12582912);                   // 1536 f32
  float* bias_kvq_y = (float*)(ws + 12589056);                   // 1536 f32
  unsigned short* XLN  = (unsigned short*)(ws + 12595200);   // 32768x512; later attnout_x
  unsigned short* YLN  = (unsigned short*)(ws + 46149632);   // 32768x512; later attnout_y
  unsigned short* KVQX = (unsigned short*)(ws + 79704064);   // 32768x1536; later x2ln
  unsigned short* KVQY = (unsigned short*)(ws + 180367360);  // 32768x1536; later y2ln
  unsigned short* HBUF = (unsigned short*)(ws + 281030656);  // 32768x2048, shared x->y

  float* out_x = (float*)d_out;
  float* out_y = out_x + 16777216;

  // 1. weight transposes (f32 KxN -> bf16 NxK); q fused behind kv
  transpose_w<<<dim3(16, 8), 256, 0, stream>>>(w_qkv, wT_kvq_x, 512, 1024);
  transpose_w<<<dim3(8, 8), 256, 0, stream>>>(w_qx, wT_kvq_x + 1024 * 512, 512, 512);
  transpose_w<<<dim3(16, 8), 256, 0, stream>>>(w_qkv_y, wT_kvq_y, 512, 1024);
  transpose_w<<<dim3(8, 8), 256, 0, stream>>>(w_qy, wT_kvq_y + 1024 * 512, 512, 512);
  transpose_w<<<dim3(8, 8), 256, 0, stream>>>(w_proj, w_projT, 512, 512);
  transpose_w<<<dim3(8, 8), 256, 0, stream>>>(w_proj_y, w_projyT, 512, 512);
  transpose_w<<<dim3(32, 8), 256, 0, stream>>>(w_fc1, w_fc1T, 512, 2048);
  transpose_w<<<dim3(8, 32), 256, 0, stream>>>(w_fc2, w_fc2T, 2048, 512);
  transpose_w<<<dim3(32, 8), 256, 0, stream>>>(w_fc1y, w_fc1yT, 512, 2048);
  transpose_w<<<dim3(8, 32), 256, 0, stream>>>(w_fc2y, w_fc2yT, 2048, 512);

  hipMemcpyAsync(bias_kvq_x, b_qkv, 1024 * 4, hipMemcpyDeviceToDevice, stream);
  hipMemcpyAsync(bias_kvq_x + 1024, b_qx, 512 * 4, hipMemcpyDeviceToDevice, stream);
  hipMemcpyAsync(bias_kvq_y, b_qkv_y, 1024 * 4, hipMemcpyDeviceToDevice, stream);
  hipMemcpyAsync(bias_kvq_y + 1024, b_qy, 512 * 4, hipMemcpyDeviceToDevice, stream);

  // 2. LN1 / LN3
  ln_bf16<<<8192, 256, 0, stream>>>(x, g1, b1, XLN);
  ln_bf16<<<8192, 256, 0, stream>>>(y, g3, b3, YLN);

  // 3. fused kv|q projections, x & y batched (z)
  const float qscale = 0.17677669529663687f;  // 1/sqrt(32)
  {
    PairArgs pa{XLN, YLN, wT_kvq_x, wT_kvq_y, bias_kvq_x, bias_kvq_y,
                nullptr, nullptr, KVQX, KVQY};
    gemm256<4><<<dim3(6, 128, 2), 512, 0, stream>>>(pa, qscale, NTOK, 1536, 512);
  }

  // 4. windowed attention
  attn_win<<<512, 256, 0, stream>>>(KVQY + 1024, 1536, KVQX, 1536, 512, nmk, rpb, XLN);
  attn_win<<<512, 256, 0, stream>>>(KVQX + 1024, 1536, KVQY, 1536, 512, nmk, rpb, YLN);

  // 5. proj + residual -> d_out, batched
  {
    PairArgs pa{XLN, YLN, w_projT, w_projyT, b_proj, b_proj_y, x, y, out_x, out_y};
    gemm256<3><<<dim3(2, 128, 2), 512, 0, stream>>>(pa, 1.f, NTOK, 512, 512);
  }

  // 6. LN2 / LN4 (into dead KVQ areas)
  ln_bf16<<<8192, 256, 0, stream>>>(out_x, g2, b2, KVQX);
  ln_bf16<<<8192, 256, 0, stream>>>(out_y, g4, b4, KVQY);

  // 7. MLP x
  {
    PairArgs pa{KVQX, KVQX, w_fc1T, w_fc1T, b_fc1, b_fc1, nullptr, nullptr, HBUF, HBUF};
    gemm256<2><<<dim3(8, 128, 1), 512, 0, stream>>>(pa, 1.f, NTOK, 2048, 512);
  }
  {
    PairArgs pa{HBUF, HBUF, w_fc2T, w_fc2T, b_fc2, b_fc2, out_x, out_x, out_x, out_x};
    gemm256<3><<<dim3(2, 128, 1), 512, 0, stream>>>(pa, 1.f, NTOK, 512, 2048);
  }
  // 8. MLP y
  {
    PairArgs pa{KVQY, KVQY, w_fc1yT, w_fc1yT, b_fc1y, b_fc1y, nullptr, nullptr, HBUF, HBUF};
    gemm256<2><<<dim3(8, 128, 1), 512, 0, stream>>>(pa, 1.f, NTOK, 2048, 512);
  }
  {
    PairArgs pa{HBUF, HBUF, w_fc2yT, w_fc2yT, b_fc2y, b_fc2y, out_y, out_y, out_y, out_y};
    gemm256<3><<<dim3(2, 128, 1), 512, 0, stream>>>(pa, 1.f, NTOK, 512, 2048);
  }
}

// Round 4
// 1139.715 us; speedup vs baseline: 1.2569x; 1.0468x over previous
//
#include <hip/hip_runtime.h>

// MixTransformerBlock on MI355X (gfx950).
// Round 4: gemm256 phases restructured to the exact m201 template shape:
// {ds_read ; stage ; [vmcnt] ; barrier ; lgkmcnt(0) ; MFMA ; barrier}.
// Requires ws_size >= ~416 MB.

typedef __attribute__((ext_vector_type(8))) short bf16x8;
typedef __attribute__((ext_vector_type(4))) float f32x4;

#define NTOK 32768   // B * H * W
#define CDIM 512

__device__ __forceinline__ unsigned short f2bf(float f) {
  unsigned int u = __float_as_uint(f);
  u = (u + 0x7fffu + ((u >> 16) & 1u)) >> 16;   // RNE (inputs finite)
  return (unsigned short)u;
}

__device__ __forceinline__ void gload_lds16(const void* g, void* l) {
  __builtin_amdgcn_global_load_lds(
      (const __attribute__((address_space(1))) void*)g,
      (__attribute__((address_space(3))) void*)l, 16, 0, 0);
}

// ---------------------------------------------------------------- transpose
__global__ __launch_bounds__(256)
void transpose_w(const float* __restrict__ W, unsigned short* __restrict__ Wt,
                 int K, int N) {
  __shared__ float tile[64][65];
  const int n0 = blockIdx.x * 64, k0 = blockIdx.y * 64;
  const int c = threadIdx.x & 63, rb = threadIdx.x >> 6;
#pragma unroll
  for (int i = 0; i < 16; ++i) {
    int r = i * 4 + rb;
    tile[r][c] = W[(long)(k0 + r) * N + n0 + c];
  }
  __syncthreads();
#pragma unroll
  for (int i = 0; i < 16; ++i) {
    int rn = i * 4 + rb;
    Wt[(long)(n0 + rn) * K + k0 + c] = f2bf(tile[c][rn]);
  }
}

// ---------------------------------------------------------------- layernorm
__global__ __launch_bounds__(256)
void ln_bf16(const float* __restrict__ X, const float* __restrict__ g,
             const float* __restrict__ b, unsigned short* __restrict__ out) {
  const int lane = threadIdx.x & 63;
  const int wid = threadIdx.x >> 6;
  const long t = (long)blockIdx.x * 4 + wid;
  const float* x = X + t * CDIM + lane * 8;
  float4 v0 = *(const float4*)x;
  float4 v1 = *(const float4*)(x + 4);
  float s = v0.x + v0.y + v0.z + v0.w + v1.x + v1.y + v1.z + v1.w;
  float sq = v0.x * v0.x + v0.y * v0.y + v0.z * v0.z + v0.w * v0.w +
             v1.x * v1.x + v1.y * v1.y + v1.z * v1.z + v1.w * v1.w;
#pragma unroll
  for (int off = 32; off; off >>= 1) {
    s += __shfl_xor(s, off);
    sq += __shfl_xor(sq, off);
  }
  const float mean = s * (1.0f / 512.0f);
  const float var = sq * (1.0f / 512.0f) - mean * mean;
  const float rs = rsqrtf(var + 1e-4f);
  float4 g0 = *(const float4*)(g + lane * 8);
  float4 g1 = *(const float4*)(g + lane * 8 + 4);
  float4 b0 = *(const float4*)(b + lane * 8);
  float4 b1 = *(const float4*)(b + lane * 8 + 4);
  bf16x8 r;
  r[0] = (short)f2bf((v0.x - mean) * rs * g0.x + b0.x);
  r[1] = (short)f2bf((v0.y - mean) * rs * g0.y + b0.y);
  r[2] = (short)f2bf((v0.z - mean) * rs * g0.z + b0.z);
  r[3] = (short)f2bf((v0.w - mean) * rs * g0.w + b0.w);
  r[4] = (short)f2bf((v1.x - mean) * rs * g1.x + b1.x);
  r[5] = (short)f2bf((v1.y - mean) * rs * g1.y + b1.y);
  r[6] = (short)f2bf((v1.z - mean) * rs * g1.z + b1.z);
  r[7] = (short)f2bf((v1.w - mean) * rs * g1.w + b1.w);
  *(bf16x8*)(out + t * CDIM + lane * 8) = r;
}

// ---------------------------------------------------------------- GEMM 256^2
// C(M,N) = A(M,K) @ Bt(N,K)^T, bf16 in, fp32 accum. 8-phase schedule.
// EPI 2: out bf16 gelu_exact(+bias)
// EPI 3: out f32  (+bias + resid)
// EPI 4: out bf16 (+bias), * scale for cols >= 1024  (fused kv|q projection)

struct PairArgs {
  const unsigned short* A0; const unsigned short* A1;
  const unsigned short* B0; const unsigned short* B1;
  const float* bias0; const float* bias1;
  const float* r0; const float* r1;
  void* o0; void* o1;
};

template <int EPI>
__global__ __launch_bounds__(512, 2)
void gemm256(PairArgs pa, float scale, int M, int N, int K) {
  __shared__ __attribute__((aligned(16))) char lds[131072];

  const int z = blockIdx.z;
  const unsigned short* __restrict__ A  = z ? pa.A1 : pa.A0;
  const unsigned short* __restrict__ Bt = z ? pa.B1 : pa.B0;
  const float* __restrict__ bias = z ? pa.bias1 : pa.bias0;
  const float* resid = z ? pa.r1 : pa.r0;
  void* outp = z ? pa.o1 : pa.o0;

  // T1: bijective XCD-aware remap (m204 form)
  const int nwg = gridDim.x * gridDim.y;
  int wg = blockIdx.y * gridDim.x + blockIdx.x;
  {
    const int q8 = nwg >> 3, r8 = nwg & 7;
    const int xcd = wg & 7, o = wg >> 3;
    wg = (xcd < r8 ? xcd * (q8 + 1) : r8 * (q8 + 1) + (xcd - r8) * q8) + o;
  }
  const int bx = wg % gridDim.x, by = wg / gridDim.x;

  const int tid = threadIdx.x;
  const int lane = tid & 63;
  const int wid = tid >> 6;        // 0..7
  const int wr = wid >> 2;         // 0..1  (M half)
  const int wc = wid & 3;          // 0..3  (N quarter)
  const long rowBase = (long)by * 256;
  const long colBase = (long)bx * 256;

  const unsigned short* Ap = A + rowBase * K;
  const unsigned short* Bp = Bt + colBase * K;

  // staging: linear LDS dest, XOR-permuted global source col-slot (T2 via
  // pre-swizzled source; involution matches the ds_read XOR — rule #21).
  const int srow = wid * 8 + (lane >> 3);
  const int scol = ((lane & 7) ^ (lane >> 3)) * 8;   // elems
  const int sdst = wid * 1024;

  auto stA = [&](int buf, int k0, int i) {
    gload_lds16(Ap + (long)(i * 64 + srow) * K + k0 + scol,
                lds + buf * 65536 + i * 8192 + sdst);
  };
  auto stB = [&](int buf, int k0, int i) {
    gload_lds16(Bp + (long)(i * 64 + srow) * K + k0 + scol,
                lds + buf * 65536 + 32768 + i * 8192 + sdst);
  };

  const int lo = lane & 15;
  const int hi = lane >> 4;
  const int x7 = lane & 7;
  const int arow0 = (wr * 128 + lo) * 128;   // bytes within A region
  const int brow0 = (wc * 64 + lo) * 128;    // bytes within B region

  f32x4 acc[8][4] = {};
  bf16x8 aA[4][2], bB0[2][2], bB1[2][2];

  const int nt = K / 64;

  // prologue: tile 0 -> buf 0; issue order A0,A2,B0..B3 (needed first), A1,A3
  stA(0, 0, 0); stA(0, 0, 2); stB(0, 0, 0); stB(0, 0, 1);
  stB(0, 0, 2); stB(0, 0, 3); stA(0, 0, 1); stA(0, 0, 3);
  asm volatile("s_waitcnt vmcnt(2)" ::: "memory");
  __builtin_amdgcn_s_barrier();

  for (int t = 0; t < nt; ++t) {
    const int cur = t & 1;
    const int abase = cur * 65536;
    const int bbase = abase + 32768;
    const int k1 = (t + 1) * 64;
    const bool pf = (t + 1 < nt);

    // ---------- P0: read aA_lo + bB0 | stage A0,A2(t+1)
#pragma unroll
    for (int kk = 0; kk < 2; ++kk) {
      const int cb = ((kk * 4 + hi) ^ x7) * 16;
#pragma unroll
      for (int m = 0; m < 4; ++m)
        aA[m][kk] = *(const bf16x8*)(lds + abase + arow0 + m * 2048 + cb);
#pragma unroll
      for (int n = 0; n < 2; ++n)
        bB0[n][kk] = *(const bf16x8*)(lds + bbase + brow0 + n * 2048 + cb);
    }
    if (pf) { stA(cur ^ 1, k1, 0); stA(cur ^ 1, k1, 2); }
    __builtin_amdgcn_sched_barrier(0);
    __builtin_amdgcn_s_barrier();
    asm volatile("s_waitcnt lgkmcnt(0)" ::: "memory");
    __builtin_amdgcn_sched_barrier(0);
    __builtin_amdgcn_s_setprio(1);
#pragma unroll
    for (int kk = 0; kk < 2; ++kk)
#pragma unroll
      for (int m = 0; m < 4; ++m)
#pragma unroll
        for (int n = 0; n < 2; ++n)
          acc[m][n] = __builtin_amdgcn_mfma_f32_16x16x32_bf16(aA[m][kk], bB0[n][kk], acc[m][n], 0, 0, 0);
    __builtin_amdgcn_s_setprio(0);
    __builtin_amdgcn_s_barrier();

    // ---------- P1: read bB1 | stage B0,B1(t+1) | vmcnt(4/0)
#pragma unroll
    for (int kk = 0; kk < 2; ++kk) {
      const int cb = ((kk * 4 + hi) ^ x7) * 16;
#pragma unroll
      for (int n = 0; n < 2; ++n)
        bB1[n][kk] = *(const bf16x8*)(lds + bbase + brow0 + 4096 + n * 2048 + cb);
    }
    if (pf) {
      stB(cur ^ 1, k1, 0); stB(cur ^ 1, k1, 1);
      asm volatile("s_waitcnt vmcnt(4)" ::: "memory");   // oldest 2 (A1,A3 of t) landed
    } else {
      asm volatile("s_waitcnt vmcnt(0)" ::: "memory");
    }
    __builtin_amdgcn_sched_barrier(0);
    __builtin_amdgcn_s_barrier();
    asm volatile("s_waitcnt lgkmcnt(0)" ::: "memory");
    __builtin_amdgcn_sched_barrier(0);
    __builtin_amdgcn_s_setprio(1);
#pragma unroll
    for (int kk = 0; kk < 2; ++kk)
#pragma unroll
      for (int m = 0; m < 4; ++m)
#pragma unroll
        for (int n = 0; n < 2; ++n)
          acc[m][2 + n] = __builtin_amdgcn_mfma_f32_16x16x32_bf16(aA[m][kk], bB1[n][kk], acc[m][2 + n], 0, 0, 0);
    __builtin_amdgcn_s_setprio(0);
    __builtin_amdgcn_s_barrier();

    // ---------- P2: read aA_hi | stage B2,B3(t+1)
#pragma unroll
    for (int kk = 0; kk < 2; ++kk) {
      const int cb = ((kk * 4 + hi) ^ x7) * 16;
#pragma unroll
      for (int m = 0; m < 4; ++m)
        aA[m][kk] = *(const bf16x8*)(lds + abase + arow0 + 8192 + m * 2048 + cb);
    }
    if (pf) { stB(cur ^ 1, k1, 2); stB(cur ^ 1, k1, 3); }
    __builtin_amdgcn_sched_barrier(0);
    __builtin_amdgcn_s_barrier();
    asm volatile("s_waitcnt lgkmcnt(0)" ::: "memory");
    __builtin_amdgcn_sched_barrier(0);
    __builtin_amdgcn_s_setprio(1);
#pragma unroll
    for (int kk = 0; kk < 2; ++kk)
#pragma unroll
      for (int m = 0; m < 4; ++m)
#pragma unroll
        for (int n = 0; n < 2; ++n)
          acc[4 + m][2 + n] = __builtin_amdgcn_mfma_f32_16x16x32_bf16(aA[m][kk], bB1[n][kk], acc[4 + m][2 + n], 0, 0, 0);
    __builtin_amdgcn_s_setprio(0);
    __builtin_amdgcn_s_barrier();

    // ---------- P3: reg-only MFMA | stage A1,A3(t+1) | vmcnt(2)
    if (pf) { stA(cur ^ 1, k1, 1); stA(cur ^ 1, k1, 3); }
    __builtin_amdgcn_s_setprio(1);
#pragma unroll
    for (int kk = 0; kk < 2; ++kk)
#pragma unroll
      for (int m = 0; m < 4; ++m)
#pragma unroll
        for (int n = 0; n < 2; ++n)
          acc[4 + m][n] = __builtin_amdgcn_mfma_f32_16x16x32_bf16(aA[m][kk], bB0[n][kk], acc[4 + m][n], 0, 0, 0);
    __builtin_amdgcn_s_setprio(0);
    if (pf) asm volatile("s_waitcnt vmcnt(2)" ::: "memory");  // tile t+1 first-6 landed
    __builtin_amdgcn_sched_barrier(0);
    __builtin_amdgcn_s_barrier();
  }

  // -------- epilogue
#pragma unroll
  for (int m = 0; m < 8; ++m) {
    const long rbase = rowBase + wr * 128 + m * 16 + hi * 4;
#pragma unroll
    for (int n = 0; n < 4; ++n) {
      const long col = colBase + wc * 64 + n * 16 + lo;
      const float bv = bias[col];
#pragma unroll
      for (int r = 0; r < 4; ++r) {
        float v = acc[m][n][r] + bv;
        if constexpr (EPI == 2) v = 0.5f * v * (1.0f + erff(v * 0.70710678118654752f));
        if constexpr (EPI == 4) { if (col >= 1024) v *= scale; }
        const long idx = (rbase + r) * (long)N + col;
        if constexpr (EPI == 3) {
          ((float*)outp)[idx] = v + resid[idx];
        } else {
          ((unsigned short*)outp)[idx] = f2bf(v);
        }
      }
    }
  }
}

// ---------------------------------------------------------------- attention
__global__ __launch_bounds__(256)
void attn_win(const unsigned short* __restrict__ qbuf, int qs,
              const unsigned short* __restrict__ kvbuf, int ks_, int vOff,
              const float* __restrict__ nmask,
              const float* __restrict__ rpb,
              unsigned short* __restrict__ obuf) {
  __shared__ float nm_s[64];
  __shared__ unsigned short P_s[4][64][72];
  __shared__ unsigned short Vt_s[4][32][72];

  const int tid = threadIdx.x;
  const int lane = tid & 63;
  const int wid = tid >> 6;
  const int wi = blockIdx.x;
  const int wbase = (wi >> 6) * 4096 + ((wi >> 3) & 7) * 512 + (wi & 7) * 8;

  if (tid < 64) nm_s[tid] = nmask[wbase + ((tid >> 3) << 6) + (tid & 7)];
  __syncthreads();

  const int r0 = (lane >> 4) * 4;
  const int cn = lane & 15;
  const int kb8 = (lane >> 4) * 8;

  for (int hi = 0; hi < 4; ++hi) {
    const int h = wid * 4 + hi;

    f32x4 s[4][4] = {};
    {
      bf16x8 qa[4], kb[4];
#pragma unroll
      for (int m = 0; m < 4; ++m) {
        const int r = m * 16 + cn;
        const long tok = wbase + ((r >> 3) << 6) + (r & 7);
        qa[m] = *(const bf16x8*)(qbuf + tok * qs + h * 32 + kb8);
      }
#pragma unroll
      for (int n = 0; n < 4; ++n) {
        const int c = n * 16 + cn;
        const long tok = wbase + ((c >> 3) << 6) + (c & 7);
        kb[n] = *(const bf16x8*)(kvbuf + tok * ks_ + h * 32 + kb8);
      }
#pragma unroll
      for (int m = 0; m < 4; ++m)
#pragma unroll
        for (int n = 0; n < 4; ++n)
          s[m][n] = __builtin_amdgcn_mfma_f32_16x16x32_bf16(qa[m], kb[n], s[m][n], 0, 0, 0);
    }

#pragma unroll
    for (int m = 0; m < 4; ++m) {
#pragma unroll
      for (int r = 0; r < 4; ++r) {
        const int q = m * 16 + r0 + r;
        const int qi = q >> 3, qj = q & 7;
        float rowv[4];
#pragma unroll
        for (int n = 0; n < 4; ++n) {
          const int k = n * 16 + cn;
          const int ki = k >> 3, kj = k & 7;
          const int ridx = (qi - ki + 7) * 15 + (qj - kj + 7);
          rowv[n] = s[m][n][r] + rpb[ridx * 16 + h] + nm_s[q] + nm_s[k];
        }
        float mx = fmaxf(fmaxf(rowv[0], rowv[1]), fmaxf(rowv[2], rowv[3]));
#pragma unroll
        for (int off = 8; off; off >>= 1) mx = fmaxf(mx, __shfl_xor(mx, off));
        float sum = 0.f;
#pragma unroll
        for (int n = 0; n < 4; ++n) { rowv[n] = __expf(rowv[n] - mx); sum += rowv[n]; }
#pragma unroll
        for (int off = 8; off; off >>= 1) sum += __shfl_xor(sum, off);
        const float inv = 1.0f / sum;
#pragma unroll
        for (int n = 0; n < 4; ++n) s[m][n][r] = rowv[n] * inv;
      }
    }

#pragma unroll
    for (int m = 0; m < 4; ++m)
#pragma unroll
      for (int n = 0; n < 4; ++n)
#pragma unroll
        for (int r = 0; r < 4; ++r)
          P_s[wid][m * 16 + r0 + r][n * 16 + cn] = f2bf(s[m][n][r]);

    {
      const long tok = wbase + ((lane >> 3) << 6) + (lane & 7);
      const unsigned short* vrow = kvbuf + tok * ks_ + vOff + h * 32;
#pragma unroll
      for (int j = 0; j < 4; ++j) {
        bf16x8 vv = *(const bf16x8*)(vrow + j * 8);
#pragma unroll
        for (int e = 0; e < 8; ++e)
          Vt_s[wid][j * 8 + e][lane] = (unsigned short)vv[e];
      }
    }

    f32x4 o[4][2] = {};
#pragma unroll
    for (int t = 0; t < 2; ++t) {
      bf16x8 pa[4], vb[2];
#pragma unroll
      for (int m = 0; m < 4; ++m)
        pa[m] = *(const bf16x8*)(&P_s[wid][m * 16 + cn][t * 32 + kb8]);
#pragma unroll
      for (int n = 0; n < 2; ++n)
        vb[n] = *(const bf16x8*)(&Vt_s[wid][n * 16 + cn][t * 32 + kb8]);
#pragma unroll
      for (int m = 0; m < 4; ++m)
#pragma unroll
        for (int n = 0; n < 2; ++n)
          o[m][n] = __builtin_amdgcn_mfma_f32_16x16x32_bf16(pa[m], vb[n], o[m][n], 0, 0, 0);
    }

#pragma unroll
    for (int m = 0; m < 4; ++m) {
#pragma unroll
      for (int r = 0; r < 4; ++r) {
        const int q = m * 16 + r0 + r;
        const long tok = wbase + ((q >> 3) << 6) + (q & 7);
#pragma unroll
        for (int n = 0; n < 2; ++n)
          obuf[tok * 512 + h * 32 + n * 16 + cn] = f2bf(o[m][n][r]);
      }
    }
  }
}

// ---------------------------------------------------------------- launch
extern "C" void kernel_launch(void* const* d_in, const int* in_sizes, int n_in,
                              void* d_out, int out_size, void* d_ws, size_t ws_size,
                              hipStream_t stream) {
  const float* x = (const float*)d_in[0];
  const float* y = (const float*)d_in[1];
  const float* nmk = (const float*)d_in[2];
  const float* rpb = (const float*)d_in[3];
  const float* g1 = (const float*)d_in[4];
  const float* b1 = (const float*)d_in[5];
  const float* g3 = (const float*)d_in[6];
  const float* b3 = (const float*)d_in[7];
  const float* w_qkv = (const float*)d_in[8];
  const float* b_qkv = (const float*)d_in[9];
  const float* w_qkv_y = (const float*)d_in[10];
  const float* b_qkv_y = (const float*)d_in[11];
  const float* w_qx = (const float*)d_in[12];
  const float* b_qx = (const float*)d_in[13];
  const float* w_qy = (const float*)d_in[14];
  const float* b_qy = (const float*)d_in[15];
  const float* w_proj = (const float*)d_in[16];
  const float* b_proj = (const float*)d_in[17];
  const float* w_proj_y = (const float*)d_in[18];
  const float* b_proj_y = (const float*)d_in[19];
  const float* g2 = (const float*)d_in[20];
  const float* b2 = (const float*)d_in[21];
  const float* g4 = (const float*)d_in[22];
  const float* b4 = (const float*)d_in[23];
  const float* w_fc1 = (const float*)d_in[24];
  const float* b_fc1 = (const float*)d_in[25];
  const float* w_fc2 = (const float*)d_in[26];
  const float* b_fc2 = (const float*)d_in[27];
  const float* w_fc1y = (const float*)d_in[28];
  const float* b_fc1y = (const float*)d_in[29];
  const float* w_fc2y = (const float*)d_in[30];
  const float* b_fc2y = (const float*)d_in[31];

  char* ws = (char*)d_ws;
  unsigned short* wT_kvq_x = (unsigned short*)(ws + 0);          // 1536x512
  unsigned short* wT_kvq_y = (unsigned short*)(ws + 1572864);    // 1536x512
  unsigned short* w_projT  = (unsigned short*)(ws + 3145728);    // 512x512
  unsigned short* w_projyT = (unsigned short*)(ws + 3670016);
  unsigned short* w_fc1T   = (unsigned short*)(ws + 4194304);    // 2048x512
  unsigned short* w_fc2T   = (unsigned short*)(ws + 6291456);    // 512x2048
  unsigned short* w_fc1yT  = (unsigned short*)(ws + 8388608);
  unsigned short* w_fc2yT  = (unsigned short*)(ws + 10485760);
  float* bias_kvq_x = (float*)(ws + 12582912);                   // 1536 f32
  float* bias_kvq_y = (float*)(ws + 12589056);                   // 1536 f32
  unsigned short* XLN  = (unsigned short*)(ws + 12595200);   // 32768x512; later attnout_x
  unsigned short* YLN  = (unsigned short*)(ws + 46149632);   // 32768x512; later attnout_y
  unsigned short* KVQX = (unsigned short*)(ws + 79704064);   // 32768x1536; later x2ln
  unsigned short* KVQY = (unsigned short*)(ws + 180367360);  // 32768x1536; later y2ln
  unsigned short* HBUF = (unsigned short*)(ws + 281030656);  // 32768x2048, shared x->y

  float* out_x = (float*)d_out;
  float* out_y = out_x + 16777216;

  // 1. weight transposes (f32 KxN -> bf16 NxK); q fused behind kv
  transpose_w<<<dim3(16, 8), 256, 0, stream>>>(w_qkv, wT_kvq_x, 512, 1024);
  transpose_w<<<dim3(8, 8), 256, 0, stream>>>(w_qx, wT_kvq_x + 1024 * 512, 512, 512);
  transpose_w<<<dim3(16, 8), 256, 0, stream>>>(w_qkv_y, wT_kvq_y, 512, 1024);
  transpose_w<<<dim3(8, 8), 256, 0, stream>>>(w_qy, wT_kvq_y + 1024 * 512, 512, 512);
  transpose_w<<<dim3(8, 8), 256, 0, stream>>>(w_proj, w_projT, 512, 512);
  transpose_w<<<dim3(8, 8), 256, 0, stream>>>(w_proj_y, w_projyT, 512, 512);
  transpose_w<<<dim3(32, 8), 256, 0, stream>>>(w_fc1, w_fc1T, 512, 2048);
  transpose_w<<<dim3(8, 32), 256, 0, stream>>>(w_fc2, w_fc2T, 2048, 512);
  transpose_w<<<dim3(32, 8), 256, 0, stream>>>(w_fc1y, w_fc1yT, 512, 2048);
  transpose_w<<<dim3(8, 32), 256, 0, stream>>>(w_fc2y, w_fc2yT, 2048, 512);

  hipMemcpyAsync(bias_kvq_x, b_qkv, 1024 * 4, hipMemcpyDeviceToDevice, stream);
  hipMemcpyAsync(bias_kvq_x + 1024, b_qx, 512 * 4, hipMemcpyDeviceToDevice, stream);
  hipMemcpyAsync(bias_kvq_y, b_qkv_y, 1024 * 4, hipMemcpyDeviceToDevice, stream);
  hipMemcpyAsync(bias_kvq_y + 1024, b_qy, 512 * 4, hipMemcpyDeviceToDevice, stream);

  // 2. LN1 / LN3
  ln_bf16<<<8192, 256, 0, stream>>>(x, g1, b1, XLN);
  ln_bf16<<<8192, 256, 0, stream>>>(y, g3, b3, YLN);

  // 3. fused kv|q projections, x & y batched (z)
  const float qscale = 0.17677669529663687f;  // 1/sqrt(32)
  {
    PairArgs pa{XLN, YLN, wT_kvq_x, wT_kvq_y, bias_kvq_x, bias_kvq_y,
                nullptr, nullptr, KVQX, KVQY};
    gemm256<4><<<dim3(6, 128, 2), 512, 0, stream>>>(pa, qscale, NTOK, 1536, 512);
  }

  // 4. windowed attention
  attn_win<<<512, 256, 0, stream>>>(KVQY + 1024, 1536, KVQX, 1536, 512, nmk, rpb, XLN);
  attn_win<<<512, 256, 0, stream>>>(KVQX + 1024, 1536, KVQY, 1536, 512, nmk, rpb, YLN);

  // 5. proj + residual -> d_out, batched
  {
    PairArgs pa{XLN, YLN, w_projT, w_projyT, b_proj, b_proj_y, x, y, out_x, out_y};
    gemm256<3><<<dim3(2, 128, 2), 512, 0, stream>>>(pa, 1.f, NTOK, 512, 512);
  }

  // 6. LN2 / LN4 (into dead KVQ areas)
  ln_bf16<<<8192, 256, 0, stream>>>(out_x, g2, b2, KVQX);
  ln_bf16<<<8192, 256, 0, stream>>>(out_y, g4, b4, KVQY);

  // 7. MLP x
  {
    PairArgs pa{KVQX, KVQX, w_fc1T, w_fc1T, b_fc1, b_fc1, nullptr, nullptr, HBUF, HBUF};
    gemm256<2><<<dim3(8, 128, 1), 512, 0, stream>>>(pa, 1.f, NTOK, 2048, 512);
  }
  {
    PairArgs pa{HBUF, HBUF, w_fc2T, w_fc2T, b_fc2, b_fc2, out_x, out_x, out_x, out_x};
    gemm256<3><<<dim3(2, 128, 1), 512, 0, stream>>>(pa, 1.f, NTOK, 512, 2048);
  }
  // 8. MLP y
  {
    PairArgs pa{KVQY, KVQY, w_fc1yT, w_fc1yT, b_fc1y, b_fc1y, nullptr, nullptr, HBUF, HBUF};
    gemm256<2><<<dim3(8, 128, 1), 512, 0, stream>>>(pa, 1.f, NTOK, 2048, 512);
  }
  {
    PairArgs pa{HBUF, HBUF, w_fc2yT, w_fc2yT, b_fc2y, b_fc2y, out_y, out_y, out_y, out_y};
    gemm256<3><<<dim3(2, 128, 1), 512, 0, stream>>>(pa, 1.f, NTOK, 512, 2048);
  }
}